// Round 10
// baseline (130.266 us; speedup 1.0000x reference)
//
#include <hip/hip_runtime.h>
#include <math.h>
#include <float.h>

#define ROWS 1000000
#define NTHR 256
#define K1_BLOCKS 512
#define K1_TOTAL (K1_BLOCKS * NTHR)   // 131072 threads
#define K1_ITERS 8                    // 131072*8 = 1,048,576 >= ROWS
#define NEG_BIG (-3.0e38f)

// ---------------------------------------------------------------------------
// K0: front (1 block x 128) — byte-identical to the round-6 PASSING version,
// plus zeroing of the ctl/counter words used by the last-block sync.
// ---------------------------------------------------------------------------
__global__ __launch_bounds__(128) void front_kernel(
    const int* __restrict__ x, const float* __restrict__ hidden, const int* __restrict__ pos,
    const float* __restrict__ loc_emb, const float* __restrict__ arr_emb,
    const float* __restrict__ dur_emb, const float* __restrict__ pos_emb,
    const float* __restrict__ f1rW1, const float* __restrict__ f1rb1,
    const float* __restrict__ f1rW2, const float* __restrict__ f1rb2,
    const float* __restrict__ f1W,   const float* __restrict__ f1b,
    const float* __restrict__ f2rW1, const float* __restrict__ f2rb1,
    const float* __restrict__ f2rW2, const float* __restrict__ f2rb2,
    const float* __restrict__ f2W,   const float* __restrict__ f2b,
    const float* __restrict__ f3rW1, const float* __restrict__ f3rb1,
    const float* __restrict__ f3rW2, const float* __restrict__ f3rb2,
    const float* __restrict__ f3W,   const float* __restrict__ f3b,
    const float* __restrict__ ln_g,  const float* __restrict__ ln_b,
    const float* __restrict__ ode_W, const float* __restrict__ ode_b,
    const float* __restrict__ oW1,   const float* __restrict__ ob1,
    const float* __restrict__ oW2,   const float* __restrict__ ob2,
    const float* __restrict__ fc5_W, const float* __restrict__ fc5_b,
    const float* __restrict__ fc6_W, const float* __restrict__ fc6_b,
    const float* __restrict__ gWih,  const float* __restrict__ gbih,
    const float* __restrict__ gWhh,  const float* __restrict__ gbhh,
    float* __restrict__ out, float* __restrict__ ws)
{
    __shared__ float e[3][16], tr[3][16], h1[3][16];
    __shared__ float praw[15], pnorm[15];
    __shared__ float ode0[32], odt[32], hvec[32], hnew[32], pe[32];
    __shared__ float gi[96], gh[96];
    __shared__ float a5[24], a6[24];
    __shared__ float red[4];

    const int t = threadIdx.x;

    // zero the sync words (device-scope release so all XCDs see fresh zeros)
    if (t == 127) {
        __hip_atomic_store((unsigned long long*)(ws + 32), 0ull,
                           __ATOMIC_RELEASE, __HIP_MEMORY_SCOPE_AGENT);
        __hip_atomic_store((unsigned int*)(ws + 34), 0u,
                           __ATOMIC_RELEASE, __HIP_MEMORY_SCOPE_AGENT);
    }

    if (t < 48) {
        int c = t >> 4, j = t & 15;
        const float* emb = (c == 0) ? (loc_emb + (size_t)x[0] * 16)
                         : (c == 1) ? (arr_emb + (size_t)x[1] * 16)
                                    : (dur_emb + (size_t)x[2] * 16);
        e[c][j] = emb[j];
    }
    if (t < 32) pe[t] = pos_emb[pos[0] * 32 + t];
    __syncthreads();

    for (int i = 0; i < 2; ++i) {
        if (t < 48) { int c = t >> 4, j = t & 15; tr[c][j] = fmaxf(e[c][j], 0.f); }
        __syncthreads();
        if (t < 48) {
            int c = t >> 4, j = t & 15;
            const float* W1 = ((c == 0) ? f1rW1 : (c == 1) ? f2rW1 : f3rW1) + i * 256 + j * 16;
            const float* b1 = ((c == 0) ? f1rb1 : (c == 1) ? f2rb1 : f3rb1) + i * 16;
            float a = b1[j];
            #pragma unroll
            for (int k = 0; k < 16; ++k) a += W1[k] * tr[c][k];
            h1[c][j] = fmaxf(a, 0.f);
        }
        __syncthreads();
        if (t < 48) {
            int c = t >> 4, j = t & 15;
            const float* W2 = ((c == 0) ? f1rW2 : (c == 1) ? f2rW2 : f3rW2) + i * 256 + j * 16;
            const float* b2 = ((c == 0) ? f1rb2 : (c == 1) ? f2rb2 : f3rb2) + i * 16;
            float a = b2[j];
            #pragma unroll
            for (int k = 0; k < 16; ++k) a += W2[k] * h1[c][k];
            e[c][j] += 0.3f * a;
        }
        __syncthreads();
    }

    if (t < 15) {
        int c = t / 5, q = t % 5;
        const float* W = ((c == 0) ? f1W : (c == 1) ? f2W : f3W) + q * 16;
        const float* b = ((c == 0) ? f1b : (c == 1) ? f2b : f3b);
        float a = b[q];
        #pragma unroll
        for (int k = 0; k < 16; ++k) a += W[k] * e[c][k];
        praw[t] = a;
    }
    __syncthreads();

    if (t == 0) {
        float mu = 0.f;
        for (int k = 0; k < 15; ++k) mu += praw[k];
        mu *= (1.f / 15.f);
        float var = 0.f;
        for (int k = 0; k < 15; ++k) { float d = praw[k] - mu; var += d * d; }
        var *= (1.f / 15.f);
        red[0] = mu;
        red[1] = rsqrtf(var + 1e-5f);
    }
    __syncthreads();
    if (t < 15) pnorm[t] = (praw[t] - red[0]) * red[1] * ln_g[t] + ln_b[t];
    if (t < 32) {
        float a = ode_b[t];
        const float* W = ode_W + t * 5;
        #pragma unroll
        for (int k = 0; k < 5; ++k) a += W[k] * praw[10 + k];
        ode0[t] = a;
    }
    __syncthreads();
    if (t < 32) {
        float a = ob1[t];
        const float* W = oW1 + t * 32;
        #pragma unroll
        for (int k = 0; k < 32; ++k) a += W[k] * fmaxf(ode0[k], 0.f);
        odt[t] = fmaxf(a, 0.f);
    }
    __syncthreads();
    if (t < 32) {
        float a = ob2[t];
        const float* W = oW2 + t * 32;
        #pragma unroll
        for (int k = 0; k < 32; ++k) a += W[k] * odt[k];
        hvec[t] = hidden[t] + ode0[t] + 0.3f * a;
    }
    __syncthreads();
    if (t < 96) {
        float a = gbih[t];
        const float* W = gWih + t * 15;
        #pragma unroll
        for (int k = 0; k < 15; ++k) a += W[k] * pnorm[k];
        gi[t] = a;
        float c2 = gbhh[t];
        const float* V = gWhh + t * 32;
        #pragma unroll
        for (int k = 0; k < 32; ++k) c2 += V[k] * hvec[k];
        gh[t] = c2;
    }
    __syncthreads();
    if (t < 32) {
        float r = 1.f / (1.f + expf(-(gi[t] + gh[t])));
        float z = 1.f / (1.f + expf(-(gi[32 + t] + gh[32 + t])));
        float n = tanhf(gi[64 + t] + r * gh[64 + t]);
        float hn = (1.f - z) * n + z * hvec[t];
        hnew[t] = hn;
        ws[t] = hn;
        out[ROWS + 48 + t] = hn;
    }
    __syncthreads();
    if (t < 24) {
        float a = fc5_b[t];
        const float* W = fc5_W + t * 32;
        #pragma unroll
        for (int k = 0; k < 32; ++k) a += W[k] * (hnew[k] + pe[k]);
        a5[t] = a;
        float b = fc6_b[t];
        const float* V = fc6_W + t * 32;
        #pragma unroll
        for (int k = 0; k < 32; ++k) b += V[k] * hnew[k];
        a6[t] = b;
    }
    __syncthreads();
    if (t == 0) {
        float m = -INFINITY;
        for (int k = 0; k < 24; ++k) m = fmaxf(m, a5[k]);
        float s = 0.f;
        for (int k = 0; k < 24; ++k) s += expf(a5[k] - m);
        red[2] = m + logf(s);
        m = -INFINITY;
        for (int k = 0; k < 24; ++k) m = fmaxf(m, a6[k]);
        s = 0.f;
        for (int k = 0; k < 24; ++k) s += expf(a6[k] - m);
        red[3] = m + logf(s);
    }
    __syncthreads();
    if (t < 24) {
        out[ROWS + t]      = a5[t] - red[2];
        out[ROWS + 24 + t] = a6[t] - red[3];
    }
}

// ---------------------------------------------------------------------------
// K1: grid-stride logits + last-block lse + in-register subtract. 512 blocks
// (trivially all co-resident: >=8 blocks/CU capacity at this VGPR/LDS usage),
// 8 rows/thread held in registers across the device-wide flag wait, then
// out[r] = logit - lse written exactly once.
// ---------------------------------------------------------------------------
__global__ __launch_bounds__(NTHR) void logits_kernel(
    const float* __restrict__ W, const float* __restrict__ b,
    const float* __restrict__ ws_h, float* __restrict__ out,
    unsigned long long* __restrict__ partials,   // 512 packed (m,s)
    unsigned long long* __restrict__ ctl,        // packed {flag<<63 | lse bits}
    unsigned int* __restrict__ counter)
{
    __shared__ float hs[32];
    __shared__ int isLast;
    __shared__ float lse_sh;
    const int t = threadIdx.x;
    if (t < 32) hs[t] = ws_h[t];
    __syncthreads();

    const int gid = blockIdx.x * NTHR + t;
    const float4* W4 = (const float4*)W;

    float lg[K1_ITERS];
    float m = NEG_BIG, s = 0.f;
    #pragma unroll
    for (int i = 0; i < K1_ITERS; ++i) {
        const int r = gid + i * K1_TOTAL;
        lg[i] = 0.f;
        if (r < ROWS) {
            float4 w[8];
            #pragma unroll
            for (int j = 0; j < 8; ++j) w[j] = W4[(size_t)r * 8 + j];
            float acc = b[r];
            #pragma unroll
            for (int j = 0; j < 8; ++j)
                acc += w[j].x * hs[4*j] + w[j].y * hs[4*j+1]
                     + w[j].z * hs[4*j+2] + w[j].w * hs[4*j+3];
            lg[i] = acc;
            float M = fmaxf(m, acc);                 // branchless online
            s = s * __expf(m - M) + __expf(acc - M);
            m = M;
        }
    }

    // block (m,s) reduce (R6-proven LDS tree)
    __shared__ float sm[NTHR], ss[NTHR];
    sm[t] = m; ss[t] = s;
    __syncthreads();
    for (int off = NTHR / 2; off > 0; off >>= 1) {
        if (t < off) {
            float m2 = sm[t + off], s2 = ss[t + off];
            float M  = fmaxf(sm[t], m2);
            ss[t] = ss[t] * __expf(sm[t] - M) + s2 * __expf(m2 - M);
            sm[t] = M;
        }
        __syncthreads();
    }

    if (t == 0) {
        unsigned long long pb = (unsigned long long)__float_as_uint(sm[0])
                              | ((unsigned long long)__float_as_uint(ss[0]) << 32);
        __hip_atomic_store(&partials[blockIdx.x], pb,
                           __ATOMIC_RELEASE, __HIP_MEMORY_SCOPE_AGENT);
        unsigned int old = __hip_atomic_fetch_add(counter, 1u,
                           __ATOMIC_ACQ_REL, __HIP_MEMORY_SCOPE_AGENT);
        isLast = (old == K1_BLOCKS - 1);
    }
    __syncthreads();

    if (isLast) {
        // reduce 512 partials -> lse, publish {flag|lse}
        float fm = NEG_BIG, fs = 0.f;
        for (int i = t; i < K1_BLOCKS; i += NTHR) {
            unsigned long long pb = __hip_atomic_load(&partials[i],
                                    __ATOMIC_ACQUIRE, __HIP_MEMORY_SCOPE_AGENT);
            float pm = __uint_as_float((unsigned int)pb);
            float ps = __uint_as_float((unsigned int)(pb >> 32));
            float M = fmaxf(fm, pm);
            fs = fs * __expf(fm - M) + ps * __expf(pm - M);
            fm = M;
        }
        sm[t] = fm; ss[t] = fs;
        __syncthreads();
        for (int off = NTHR / 2; off > 0; off >>= 1) {
            if (t < off) {
                float m2 = sm[t + off], s2 = ss[t + off];
                float M  = fmaxf(sm[t], m2);
                ss[t] = ss[t] * __expf(sm[t] - M) + s2 * __expf(m2 - M);
                sm[t] = M;
            }
            __syncthreads();
        }
        if (t == 0) {
            float lse = sm[0] + logf(ss[0]);
            lse_sh = lse;
            unsigned long long packed = (1ull << 63)
                                      | (unsigned long long)__float_as_uint(lse);
            __hip_atomic_store(ctl, packed,
                               __ATOMIC_RELEASE, __HIP_MEMORY_SCOPE_AGENT);
        }
        __syncthreads();
    } else {
        if (t == 0) {
            unsigned long long v; int spins = 0;
            do {
                v = __hip_atomic_load(ctl, __ATOMIC_ACQUIRE,
                                      __HIP_MEMORY_SCOPE_AGENT);
                if (v >> 63) break;
                __builtin_amdgcn_s_sleep(2);
            } while (++spins < (1 << 24));          // safety net: no hang
            lse_sh = __uint_as_float((unsigned int)v);
        }
        __syncthreads();
    }
    const float lse = lse_sh;

    #pragma unroll
    for (int i = 0; i < K1_ITERS; ++i) {
        const int r = gid + i * K1_TOTAL;
        if (r < ROWS) out[r] = lg[i] - lse;
    }
}

extern "C" void kernel_launch(void* const* d_in, const int* in_sizes, int n_in,
                              void* d_out, int out_size, void* d_ws, size_t ws_size,
                              hipStream_t stream) {
    const int*   x       = (const int*)  d_in[0];
    const float* hidden  = (const float*)d_in[1];
    const int*   pos     = (const int*)  d_in[2];
    const float* loc_emb = (const float*)d_in[3];
    const float* arr_emb = (const float*)d_in[4];
    const float* dur_emb = (const float*)d_in[5];
    const float* pos_emb = (const float*)d_in[6];
    const float* f1rW1 = (const float*)d_in[7];
    const float* f1rb1 = (const float*)d_in[8];
    const float* f1rW2 = (const float*)d_in[9];
    const float* f1rb2 = (const float*)d_in[10];
    const float* f1W   = (const float*)d_in[11];
    const float* f1b   = (const float*)d_in[12];
    const float* f2rW1 = (const float*)d_in[13];
    const float* f2rb1 = (const float*)d_in[14];
    const float* f2rW2 = (const float*)d_in[15];
    const float* f2rb2 = (const float*)d_in[16];
    const float* f2W   = (const float*)d_in[17];
    const float* f2b   = (const float*)d_in[18];
    const float* f3rW1 = (const float*)d_in[19];
    const float* f3rb1 = (const float*)d_in[20];
    const float* f3rW2 = (const float*)d_in[21];
    const float* f3rb2 = (const float*)d_in[22];
    const float* f3W   = (const float*)d_in[23];
    const float* f3b   = (const float*)d_in[24];
    const float* ln_g  = (const float*)d_in[25];
    const float* ln_b  = (const float*)d_in[26];
    const float* ode_W = (const float*)d_in[27];
    const float* ode_b = (const float*)d_in[28];
    const float* oW1   = (const float*)d_in[29];
    const float* ob1   = (const float*)d_in[30];
    const float* oW2   = (const float*)d_in[31];
    const float* ob2   = (const float*)d_in[32];
    const float* fc4_W = (const float*)d_in[33];
    const float* fc4_b = (const float*)d_in[34];
    const float* fc5_W = (const float*)d_in[35];
    const float* fc5_b = (const float*)d_in[36];
    const float* fc6_W = (const float*)d_in[37];
    const float* fc6_b = (const float*)d_in[38];
    const float* gWih  = (const float*)d_in[39];
    const float* gbih  = (const float*)d_in[40];
    const float* gWhh  = (const float*)d_in[41];
    const float* gbhh  = (const float*)d_in[42];

    float* out = (float*)d_out;
    float* wsf = (float*)d_ws;
    // ws layout (floats): [0:32) h_new ; [32] ctl u64 ; [34] counter u32 ;
    //                     [64 : 64+K1_BLOCKS*2) packed partials
    float*              ws_h        = wsf;
    unsigned long long* ws_ctl      = (unsigned long long*)(wsf + 32);
    unsigned int*       ws_counter  = (unsigned int*)(wsf + 34);
    unsigned long long* ws_partials = (unsigned long long*)(wsf + 64);

    front_kernel<<<1, 128, 0, stream>>>(
        x, hidden, pos, loc_emb, arr_emb, dur_emb, pos_emb,
        f1rW1, f1rb1, f1rW2, f1rb2, f1W, f1b,
        f2rW1, f2rb1, f2rW2, f2rb2, f2W, f2b,
        f3rW1, f3rb1, f3rW2, f3rb2, f3W, f3b,
        ln_g, ln_b, ode_W, ode_b, oW1, ob1, oW2, ob2,
        fc5_W, fc5_b, fc6_W, fc6_b, gWih, gbih, gWhh, gbhh,
        out, ws_h);

    logits_kernel<<<K1_BLOCKS, NTHR, 0, stream>>>(
        fc4_W, fc4_b, ws_h, out, ws_partials, ws_ctl, ws_counter);
}